// Round 7
// baseline (1560.716 us; speedup 1.0000x reference)
//
#include <hip/hip_runtime.h>
#include <math.h>

// DN test-mode forward, filter+rescore:
//  1) convert x -> f16 fragment-ordered tiles (2MB, LLC-resident)
//  2) f16 single-pairing MFMA GEMM (approx scores, err sigma ~4e-4 normalized)
//     + fused ||w_y|| + per-block-row max + candidate append (score >= rowmax - TAU)
//  3) global approx max per batch (gmax)
//  4) exact f32 rescore of survivors (>= gmax - TAU), packed atomicMax winner
//     (seeded with (0.0, firstInactive) to cover all gated-zero candidates)
//  5) gather out[b,z] = y2z[z,winner]/||y2z[z,:]||

typedef _Float16 half8 __attribute__((ext_vector_type(8)));
typedef __attribute__((ext_vector_type(16))) float f32x16;
typedef unsigned long long ull;

#define TAU 0.006f
#define CAP 1572864u

__device__ __forceinline__ unsigned pk2h(float a, float b) {
    union { _Float16 h; unsigned short u; } ca, cb;
    ca.h = (_Float16)a; cb.h = (_Float16)b;   // RNE
    return (unsigned)ca.u | ((unsigned)cb.u << 16);
}

// monotone-float key, smaller y wins ties
__device__ __forceinline__ ull packkey(float v, unsigned y) {
    unsigned m = __float_as_uint(v);
    m = (v >= 0.f) ? (m | 0x80000000u) : ~m;
    return ((ull)m << 32) | (ull)(0x7FFFFFFFu - y);
}

// fi = first inactive y; seed win[b]; zero append counter
__global__ __launch_bounds__(512) void init_ctrl(const int* __restrict__ age,
                                                 ull* __restrict__ win,
                                                 unsigned* __restrict__ cnt) {
    const int t = threadIdx.x;
    int fi = 0x7fffffff;
    for (int y = t; y < 32768; y += 512)
        if (age[y] < 1) fi = min(fi, y);
    __shared__ int red[512];
    red[t] = fi;
    __syncthreads();
    for (int s = 256; s; s >>= 1) {
        if (t < s) red[t] = min(red[t], red[t + s]);
        __syncthreads();
    }
    const int f = red[0];
    const ull seed = (f < 32768) ? packkey(0.0f, (unsigned)f) : packkey(-1e30f, 0u);
    win[t] = seed;                      // t < 512 = B
    if (t == 0) *cnt = 0u;
}

// x -> f16, fragment-contiguous: o = t*4096 + bx*2048 + wm*512 + mi*256 + ks*64 + lane
__global__ __launch_bounds__(512) void convert_x(const float* __restrict__ x,
                                                 uint4* __restrict__ xf16) {
    const int o = blockIdx.x * 512 + threadIdx.x;   // 262144
    const int lane = o & 63;
    const int ks = (o >> 6) & 3;
    const int mi = (o >> 8) & 1;
    const int wm = (o >> 9) & 3;
    const int bx = (o >> 11) & 1;
    const int t  = o >> 12;
    const int row = (bx << 8) + (wm << 6) + (mi << 5) + (lane & 31);
    const int col = (t << 6) + (ks << 4) + ((lane >> 5) << 3);
    const float* src = x + (size_t)row * 4096 + col;
    const float4 a = *(const float4*)src;
    const float4 b = *(const float4*)(src + 4);
    uint4 u;
    u.x = pk2h(a.x, a.y); u.y = pk2h(a.z, a.w);
    u.z = pk2h(b.x, b.y); u.w = pk2h(b.z, b.w);
    xf16[o] = u;
}

__global__ __launch_bounds__(256) void row_norms(const float* __restrict__ src,
                                                 float* __restrict__ dst, int cols) {
    const int r = blockIdx.x;
    const float* row = src + (size_t)r * cols;
    const int t = threadIdx.x;
    float s = 0.f;
    const int nIter = cols >> 10;
    for (int i = 0; i < nIter; ++i) {
        const float4 v = *reinterpret_cast<const float4*>(row + (((i << 8) + t) << 2));
        s = fmaf(v.x, v.x, s); s = fmaf(v.y, v.y, s);
        s = fmaf(v.z, v.z, s); s = fmaf(v.w, v.w, s);
    }
    #pragma unroll
    for (int off = 32; off; off >>= 1) s += __shfl_down(s, off);
    __shared__ float red[4];
    if ((t & 63) == 0) red[t >> 6] = s;
    __syncthreads();
    if (t == 0) dst[r] = sqrtf(red[0] + red[1] + red[2] + red[3]);
}

__global__ __launch_bounds__(512, 2) void gemm_f16(
    const float* __restrict__ w,      // [32768][4096]
    const uint4* __restrict__ xf16,   // pre-converted x
    const int*  __restrict__ age,
    float* __restrict__ cand,         // [512][256] block-row approx max
    float2* __restrict__ ent,         // candidate list
    unsigned* __restrict__ cnt)
{
    __shared__ uint4 Bs[2][1024];     // [buf][128 rows x 8 swizzled 16B slots]
    __shared__ float ny_inv[128];
    __shared__ float comb[256][2];
    __shared__ float rowmaxs[256];

    const int tid = threadIdx.x;
    const int bx = blockIdx.x;
    const int b0 = bx << 8;           // BM = 256
    const int y0 = blockIdx.y << 7;   // BN = 128

    // W staging: thread stages 16 consecutive f32 (slots 2q, 2q+1 of row rB)
    const int rB = tid >> 2, q = tid & 3;
    const int wi0 = (rB << 3) + ((2 * q)     ^ (rB & 7));
    const int wi1 = (rB << 3) + ((2 * q + 1) ^ (rB & 7));
    const float* bP = w + (size_t)(y0 + rB) * 4096 + (q << 4);

    // MFMA decomposition: 8 waves = 4 wm x 2 wn, wave tile 64x64, 32x32x16 f16
    const int lane = tid & 63, wave = tid >> 6;
    const int wm = wave >> 1, wn = wave & 1;
    const int kh = lane >> 5;
    const uint4* aP = xf16 + (bx << 11) + (wm << 9) + lane;

    const int rr0 = (wn << 6) + (lane & 31), rr1 = rr0 + 32;
#define BIDX(rr, ks) (((rr) << 3) + ((((ks) << 1) | kh) ^ ((rr) & 7)))
    const int i00 = BIDX(rr0, 0), i01 = BIDX(rr0, 1), i02 = BIDX(rr0, 2), i03 = BIDX(rr0, 3);
    const int i10 = BIDX(rr1, 0), i11 = BIDX(rr1, 1), i12 = BIDX(rr1, 2), i13 = BIDX(rr1, 3);

    f32x16 acc00 = (f32x16)0.0f, acc01 = (f32x16)0.0f;
    f32x16 acc10 = (f32x16)0.0f, acc11 = (f32x16)0.0f;

    half8 C0k0, C0k1, C0k2, C0k3, C1k0, C1k1, C1k2, C1k3;   // A set cur
    half8 N0k0, N0k1, N0k2, N0k3, N1k0, N1k1, N1k2, N1k3;   // A set next
    half8 b00, b01, b02, b03, b10, b11, b12, b13;           // B frags
    float4 W0, W1, W2, W3;                                  // W reg stage
    float nyacc = 0.0f;

#define MF(a, b, c) __builtin_amdgcn_mfma_f32_32x32x16_f16(a, b, c, 0, 0, 0)

#define LOADA(S, tt) { const uint4* p_ = aP + ((size_t)(tt) << 12); \
    S##0k0 = *(const half8*)(p_);        S##0k1 = *(const half8*)(p_ + 64); \
    S##0k2 = *(const half8*)(p_ + 128);  S##0k3 = *(const half8*)(p_ + 192); \
    S##1k0 = *(const half8*)(p_ + 256);  S##1k1 = *(const half8*)(p_ + 320); \
    S##1k2 = *(const half8*)(p_ + 384);  S##1k3 = *(const half8*)(p_ + 448); }

#define LOADW(tt) { const float* p_ = bP + ((tt) << 6); \
    W0 = *(const float4*)p_;       W1 = *(const float4*)(p_ + 4); \
    W2 = *(const float4*)(p_ + 8); W3 = *(const float4*)(p_ + 12); }

#define STOREB(buf) { uint4 u0, u1; \
    u0.x = pk2h(W0.x, W0.y); u0.y = pk2h(W0.z, W0.w); \
    u0.z = pk2h(W1.x, W1.y); u0.w = pk2h(W1.z, W1.w); \
    u1.x = pk2h(W2.x, W2.y); u1.y = pk2h(W2.z, W2.w); \
    u1.z = pk2h(W3.x, W3.y); u1.w = pk2h(W3.z, W3.w); \
    Bs[buf][wi0] = u0; Bs[buf][wi1] = u1; \
    nyacc = fmaf(W0.x, W0.x, nyacc); nyacc = fmaf(W0.y, W0.y, nyacc); \
    nyacc = fmaf(W0.z, W0.z, nyacc); nyacc = fmaf(W0.w, W0.w, nyacc); \
    nyacc = fmaf(W1.x, W1.x, nyacc); nyacc = fmaf(W1.y, W1.y, nyacc); \
    nyacc = fmaf(W1.z, W1.z, nyacc); nyacc = fmaf(W1.w, W1.w, nyacc); \
    nyacc = fmaf(W2.x, W2.x, nyacc); nyacc = fmaf(W2.y, W2.y, nyacc); \
    nyacc = fmaf(W2.z, W2.z, nyacc); nyacc = fmaf(W2.w, W2.w, nyacc); \
    nyacc = fmaf(W3.x, W3.x, nyacc); nyacc = fmaf(W3.y, W3.y, nyacc); \
    nyacc = fmaf(W3.z, W3.z, nyacc); nyacc = fmaf(W3.w, W3.w, nyacc); }

#define LDB01(buf) { b00 = *(const half8*)&Bs[buf][i00]; b01 = *(const half8*)&Bs[buf][i01]; \
                     b10 = *(const half8*)&Bs[buf][i10]; b11 = *(const half8*)&Bs[buf][i11]; }
#define LDB23(buf) { b02 = *(const half8*)&Bs[buf][i02]; b03 = *(const half8*)&Bs[buf][i03]; \
                     b12 = *(const half8*)&Bs[buf][i12]; b13 = *(const half8*)&Bs[buf][i13]; }

#define MFMA8_01(Ax) { __builtin_amdgcn_s_setprio(1); \
    acc00 = MF(Ax##0k0, b00, acc00); acc01 = MF(Ax##0k0, b10, acc01); \
    acc10 = MF(Ax##1k0, b00, acc10); acc11 = MF(Ax##1k0, b10, acc11); \
    acc00 = MF(Ax##0k1, b01, acc00); acc01 = MF(Ax##0k1, b11, acc01); \
    acc10 = MF(Ax##1k1, b01, acc10); acc11 = MF(Ax##1k1, b11, acc11); \
    __builtin_amdgcn_s_setprio(0); }
#define MFMA8_23(Ax) { __builtin_amdgcn_s_setprio(1); \
    acc00 = MF(Ax##0k2, b02, acc00); acc01 = MF(Ax##0k2, b12, acc01); \
    acc10 = MF(Ax##1k2, b02, acc10); acc11 = MF(Ax##1k2, b12, acc11); \
    acc00 = MF(Ax##0k3, b03, acc00); acc01 = MF(Ax##0k3, b13, acc01); \
    acc10 = MF(Ax##1k3, b03, acc10); acc11 = MF(Ax##1k3, b13, acc11); \
    __builtin_amdgcn_s_setprio(0); }

#define SBR __builtin_amdgcn_sched_barrier(0)
#define LG0 asm volatile("s_waitcnt lgkmcnt(0)" ::: "memory")

// One BK=64 iter = 2 phases; ds_writes to buf^1 complete at the writer's LG0
// before the phase-2 end barrier -> safe for next iter's LDB01.
#define TILE(cur, tt, AC, AN, GA, GW) do { \
    LDB01(cur); \
    if (GA) LOADA(AN, (tt) + 1); \
    SBR; __builtin_amdgcn_s_barrier(); LG0; SBR; \
    MFMA8_01(AC); \
    SBR; __builtin_amdgcn_s_barrier(); \
    LDB23(cur); \
    if (GA) STOREB((cur) ^ 1); \
    if (GW) LOADW((tt) + 2); \
    SBR; __builtin_amdgcn_s_barrier(); LG0; SBR; \
    MFMA8_23(AC); \
    SBR; __builtin_amdgcn_s_barrier(); \
} while (0)

    // ---- prologue ----
    LOADW(0);
    LOADA(C, 0);
    STOREB(0);     // waits W(0) via compiler vmcnt
    LOADW(1);
    SBR; LG0; SBR;
    __builtin_amdgcn_s_barrier();

    for (int t = 0; t < 62; t += 2) {
        TILE(0, t,     C, N, 1, 1);
        TILE(1, t + 1, N, C, 1, 1);
    }
    TILE(0, 62, C, N, 1, 0);
    TILE(1, 63, N, C, 0, 0);

    // ---- fused ||w_y|| ----
    float s = nyacc;
    s += __shfl_xor(s, 1);
    s += __shfl_xor(s, 2);
    if (q == 0) ny_inv[rB] = 1.0f / fmaxf(sqrtf(s), 1e-12f);
    __syncthreads();

    // ---- epilogue: gated scores, block-row max, candidate append ----
    // acc{mi}{ni}[v] = S[wm*64 + mi*32 + (v&3)+8*(v>>2)+4*kh][wn*64 + ni*32 + (lane&31)]
    const int yloc0 = (wn << 6) + (lane & 31);
    const int yloc1 = yloc0 + 32;
    const float scl0 = ny_inv[yloc0], scl1 = ny_inv[yloc1];
    const int act0 = (age[y0 + yloc0] >= 1), act1 = (age[y0 + yloc1] >= 1);
    const int rbase = (wm << 6) + (kh << 2);

#define ROWMAX_MI(ACC0, ACC1, mibase) \
    _Pragma("unroll") for (int v = 0; v < 16; ++v) { \
        float bv = fmaxf(act0 ? ACC0[v] * scl0 : 0.0f, act1 ? ACC1[v] * scl1 : 0.0f); \
        _Pragma("unroll") for (int off = 1; off < 32; off <<= 1) \
            bv = fmaxf(bv, __shfl_xor(bv, off)); \
        if ((lane & 31) == 0) comb[rbase + (mibase) + (v & 3) + ((v >> 2) << 3)][wn] = bv; \
    }
    ROWMAX_MI(acc00, acc01, 0)
    ROWMAX_MI(acc10, acc11, 32)
    __syncthreads();
    if (tid < 256) {
        const float rm = fmaxf(comb[tid][0], comb[tid][1]);
        cand[(size_t)(b0 + tid) * 256 + blockIdx.y] = rm;
        rowmaxs[tid] = rm;
    }
    __syncthreads();

#define APPEND_MI(ACC0, ACC1, mibase) \
    _Pragma("unroll") for (int v = 0; v < 16; ++v) { \
        const int r = rbase + (mibase) + (v & 3) + ((v >> 2) << 3); \
        const float thr = rowmaxs[r] - TAU; \
        if (act0) { const float sc = ACC0[v] * scl0; \
            if (sc >= thr) { const unsigned ix = atomicAdd(cnt, 1u); \
                if (ix < CAP) ent[ix] = make_float2(sc, \
                    __uint_as_float(((unsigned)(b0 + r) << 16) | (unsigned)(y0 + yloc0))); } } \
        if (act1) { const float sc = ACC1[v] * scl1; \
            if (sc >= thr) { const unsigned ix = atomicAdd(cnt, 1u); \
                if (ix < CAP) ent[ix] = make_float2(sc, \
                    __uint_as_float(((unsigned)(b0 + r) << 16) | (unsigned)(y0 + yloc1))); } } \
    }
    APPEND_MI(acc00, acc01, 0)
    APPEND_MI(acc10, acc11, 32)
#undef MF
#undef LOADA
#undef LOADW
#undef STOREB
#undef LDB01
#undef LDB23
#undef MFMA8_01
#undef MFMA8_23
#undef SBR
#undef LG0
#undef TILE
#undef BIDX
#undef ROWMAX_MI
#undef APPEND_MI
}

__global__ __launch_bounds__(256) void reduce_gmax(const float* __restrict__ cand,
                                                   float* __restrict__ gmax) {
    const int b = blockIdx.x, t = threadIdx.x;
    float m = cand[(size_t)b * 256 + t];
    #pragma unroll
    for (int off = 32; off; off >>= 1) m = fmaxf(m, __shfl_xor(m, off));
    __shared__ float sm[4];
    if ((t & 63) == 0) sm[t >> 6] = m;
    __syncthreads();
    if (t == 0) gmax[b] = fmaxf(fmaxf(sm[0], sm[1]), fmaxf(sm[2], sm[3]));
}

// exact f32 rescore of survivors; one wave per entry
__global__ __launch_bounds__(256) void rescore(
    const float* __restrict__ x, const float* __restrict__ w,
    const float* __restrict__ gmax, const float2* __restrict__ ent,
    const unsigned* __restrict__ cnt, ull* __restrict__ win)
{
    const unsigned n = min(*cnt, CAP);
    const int lane = threadIdx.x & 63;
    const unsigned wid = (blockIdx.x * 256 + threadIdx.x) >> 6;
    const unsigned nwv = (gridDim.x * 256) >> 6;
    for (unsigned e = wid; e < n; e += nwv) {
        const float2 en = ent[e];
        const unsigned by = __float_as_uint(en.y);
        const unsigned b = by >> 16, y = by & 0xffffu;
        if (en.x < gmax[b] - TAU) continue;
        const float4* xr = (const float4*)(x + (size_t)b * 4096);
        const float4* wr = (const float4*)(w + (size_t)y * 4096);
        float s = 0.f, nn = 0.f;
        #pragma unroll
        for (int k = 0; k < 16; ++k) {
            const float4 xv = xr[(k << 6) + lane];
            const float4 wv = wr[(k << 6) + lane];
            s = fmaf(xv.x, wv.x, s); s = fmaf(xv.y, wv.y, s);
            s = fmaf(xv.z, wv.z, s); s = fmaf(xv.w, wv.w, s);
            nn = fmaf(wv.x, wv.x, nn); nn = fmaf(wv.y, wv.y, nn);
            nn = fmaf(wv.z, wv.z, nn); nn = fmaf(wv.w, wv.w, nn);
        }
        #pragma unroll
        for (int off = 32; off; off >>= 1) {
            s += __shfl_xor(s, off);
            nn += __shfl_xor(nn, off);
        }
        if (lane == 0) {
            const float sc = s / fmaxf(sqrtf(nn), 1e-12f);
            atomicMax(win + b, packkey(sc, y));
        }
    }
}

__global__ __launch_bounds__(256) void gather_out(const float* __restrict__ y2z,
                                                  const float* __restrict__ nz,
                                                  const ull* __restrict__ win,
                                                  float* __restrict__ out) {
    const int g = blockIdx.x * 256 + threadIdx.x;
    if (g >= 512 * 1000) return;
    const int b = g / 1000, z = g - b * 1000;
    const unsigned lo = (unsigned)(win[b] & 0xffffffffull);
    const int yw = (int)(0x7FFFFFFFu - lo);
    out[g] = y2z[(size_t)z * 32768 + yw] / fmaxf(nz[z], 1e-12f);
}

extern "C" void kernel_launch(void* const* d_in, const int* in_sizes, int n_in,
                              void* d_out, int out_size, void* d_ws, size_t ws_size,
                              hipStream_t stream) {
    const float* x     = (const float*)d_in[0];
    const float* x2y_w = (const float*)d_in[2];
    const float* y2z_w = (const float*)d_in[3];
    const int*   y_age = (const int*)d_in[4];
    float* out = (float*)d_out;

    // ws layout (bytes)
    char* p = (char*)d_ws;
    float*    cand = (float*)p;                       // 512*256*4  = 524288
    float*    nz   = (float*)(p + 524288);            // 4096
    float*    gmax = (float*)(p + 528384);            // 2048
    ull*      win  = (ull*)(p + 530432);              // 4096
    unsigned* cnt  = (unsigned*)(p + 534528);         // 64
    uint4*    xf16 = (uint4*)(p + 534592);            // 4194304
    float2*   ent  = (float2*)(p + 4728896);          // CAP*8 = 12582912

    init_ctrl<<<1, 512, 0, stream>>>(y_age, win, cnt);
    convert_x<<<512, 512, 0, stream>>>(x, xf16);
    row_norms<<<1000, 256, 0, stream>>>(y2z_w, nz, 32768);

    gemm_f16<<<dim3(2, 256), 512, 0, stream>>>(x2y_w, xf16, y_age, cand, ent, cnt);
    reduce_gmax<<<512, 256, 0, stream>>>(cand, gmax);
    rescore<<<256, 256, 0, stream>>>(x, x2y_w, gmax, ent, cnt, win);
    gather_out<<<(512 * 1000 + 255) / 256, 256, 0, stream>>>(y2z_w, nz, win, out);
}

// Round 8
// 380.501 us; speedup vs baseline: 4.1017x; 4.1017x over previous
//
#include <hip/hip_runtime.h>
#include <math.h>

// DN test-mode forward, filter+rescore:
//  1) convert x -> f16 fragment-ordered tiles (2MB, LLC-resident)
//  2) f16 single-pairing MFMA GEMM (approx scores, err sigma ~4e-4 normalized)
//     + fused ||w_y|| + per-block-row max + candidate append (score >= rowmax - TAU)
//     Appends buffered per-block in LDS; ONE global atomicAdd per block (G12).
//  3) global approx max per batch (gmax)
//  4) exact f32 rescore of survivors (>= gmax - TAU), packed atomicMax winner
//     (seeded with (0.0, firstInactive) to cover all gated-zero candidates)
//  5) gather out[b,z] = y2z[z,winner]/||y2z[z,:]||

typedef _Float16 half8 __attribute__((ext_vector_type(8)));
typedef __attribute__((ext_vector_type(16))) float f32x16;
typedef unsigned long long ull;

#define TAU 0.006f
#define CAP 1572864u
#define LCAP 2048u

__device__ __forceinline__ unsigned pk2h(float a, float b) {
    union { _Float16 h; unsigned short u; } ca, cb;
    ca.h = (_Float16)a; cb.h = (_Float16)b;   // RNE
    return (unsigned)ca.u | ((unsigned)cb.u << 16);
}

// monotone-float key, smaller y wins ties
__device__ __forceinline__ ull packkey(float v, unsigned y) {
    unsigned m = __float_as_uint(v);
    m = (v >= 0.f) ? (m | 0x80000000u) : ~m;
    return ((ull)m << 32) | (ull)(0x7FFFFFFFu - y);
}

// fi = first inactive y; seed win[b]; zero append counter
__global__ __launch_bounds__(512) void init_ctrl(const int* __restrict__ age,
                                                 ull* __restrict__ win,
                                                 unsigned* __restrict__ cnt) {
    const int t = threadIdx.x;
    int fi = 0x7fffffff;
    for (int y = t; y < 32768; y += 512)
        if (age[y] < 1) fi = min(fi, y);
    __shared__ int red[512];
    red[t] = fi;
    __syncthreads();
    for (int s = 256; s; s >>= 1) {
        if (t < s) red[t] = min(red[t], red[t + s]);
        __syncthreads();
    }
    const int f = red[0];
    const ull seed = (f < 32768) ? packkey(0.0f, (unsigned)f) : packkey(-1e30f, 0u);
    win[t] = seed;                      // t < 512 = B
    if (t == 0) *cnt = 0u;
}

// x -> f16, fragment-contiguous: o = t*4096 + bx*2048 + wm*512 + mi*256 + ks*64 + lane
__global__ __launch_bounds__(512) void convert_x(const float* __restrict__ x,
                                                 uint4* __restrict__ xf16) {
    const int o = blockIdx.x * 512 + threadIdx.x;   // 262144
    const int lane = o & 63;
    const int ks = (o >> 6) & 3;
    const int mi = (o >> 8) & 1;
    const int wm = (o >> 9) & 3;
    const int bx = (o >> 11) & 1;
    const int t  = o >> 12;
    const int row = (bx << 8) + (wm << 6) + (mi << 5) + (lane & 31);
    const int col = (t << 6) + (ks << 4) + ((lane >> 5) << 3);
    const float* src = x + (size_t)row * 4096 + col;
    const float4 a = *(const float4*)src;
    const float4 b = *(const float4*)(src + 4);
    uint4 u;
    u.x = pk2h(a.x, a.y); u.y = pk2h(a.z, a.w);
    u.z = pk2h(b.x, b.y); u.w = pk2h(b.z, b.w);
    xf16[o] = u;
}

__global__ __launch_bounds__(256) void row_norms(const float* __restrict__ src,
                                                 float* __restrict__ dst, int cols) {
    const int r = blockIdx.x;
    const float* row = src + (size_t)r * cols;
    const int t = threadIdx.x;
    float s = 0.f;
    const int nIter = cols >> 10;
    for (int i = 0; i < nIter; ++i) {
        const float4 v = *reinterpret_cast<const float4*>(row + (((i << 8) + t) << 2));
        s = fmaf(v.x, v.x, s); s = fmaf(v.y, v.y, s);
        s = fmaf(v.z, v.z, s); s = fmaf(v.w, v.w, s);
    }
    #pragma unroll
    for (int off = 32; off; off >>= 1) s += __shfl_down(s, off);
    __shared__ float red[4];
    if ((t & 63) == 0) red[t >> 6] = s;
    __syncthreads();
    if (t == 0) dst[r] = sqrtf(red[0] + red[1] + red[2] + red[3]);
}

__global__ __launch_bounds__(512, 2) void gemm_f16(
    const float* __restrict__ w,      // [32768][4096]
    const uint4* __restrict__ xf16,   // pre-converted x
    const int*  __restrict__ age,
    float* __restrict__ cand,         // [512][256] block-row approx max
    float2* __restrict__ ent,         // candidate list
    unsigned* __restrict__ cnt)
{
    __shared__ uint4 Bs[2][1024];     // [buf][128 rows x 8 swizzled 16B slots]
    __shared__ float ny_inv[128];
    __shared__ float comb[256][2];
    __shared__ float rowmaxs[256];
    __shared__ float2 lent[LCAP];     // block-local candidate buffer
    __shared__ unsigned lcnt, gbase;

    const int tid = threadIdx.x;
    const int bx = blockIdx.x;
    const int b0 = bx << 8;           // BM = 256
    const int y0 = blockIdx.y << 7;   // BN = 128

    // W staging: thread stages 16 consecutive f32 (slots 2q, 2q+1 of row rB)
    const int rB = tid >> 2, q = tid & 3;
    const int wi0 = (rB << 3) + ((2 * q)     ^ (rB & 7));
    const int wi1 = (rB << 3) + ((2 * q + 1) ^ (rB & 7));
    const float* bP = w + (size_t)(y0 + rB) * 4096 + (q << 4);

    // MFMA decomposition: 8 waves = 4 wm x 2 wn, wave tile 64x64, 32x32x16 f16
    const int lane = tid & 63, wave = tid >> 6;
    const int wm = wave >> 1, wn = wave & 1;
    const int kh = lane >> 5;
    const uint4* aP = xf16 + (bx << 11) + (wm << 9) + lane;

    const int rr0 = (wn << 6) + (lane & 31), rr1 = rr0 + 32;
#define BIDX(rr, ks) (((rr) << 3) + ((((ks) << 1) | kh) ^ ((rr) & 7)))
    const int i00 = BIDX(rr0, 0), i01 = BIDX(rr0, 1), i02 = BIDX(rr0, 2), i03 = BIDX(rr0, 3);
    const int i10 = BIDX(rr1, 0), i11 = BIDX(rr1, 1), i12 = BIDX(rr1, 2), i13 = BIDX(rr1, 3);

    f32x16 acc00 = (f32x16)0.0f, acc01 = (f32x16)0.0f;
    f32x16 acc10 = (f32x16)0.0f, acc11 = (f32x16)0.0f;

    half8 C0k0, C0k1, C0k2, C0k3, C1k0, C1k1, C1k2, C1k3;   // A set cur
    half8 N0k0, N0k1, N0k2, N0k3, N1k0, N1k1, N1k2, N1k3;   // A set next
    half8 b00, b01, b02, b03, b10, b11, b12, b13;           // B frags
    float4 W0, W1, W2, W3;                                  // W reg stage
    float nyacc = 0.0f;

#define MF(a, b, c) __builtin_amdgcn_mfma_f32_32x32x16_f16(a, b, c, 0, 0, 0)

#define LOADA(S, tt) { const uint4* p_ = aP + ((size_t)(tt) << 12); \
    S##0k0 = *(const half8*)(p_);        S##0k1 = *(const half8*)(p_ + 64); \
    S##0k2 = *(const half8*)(p_ + 128);  S##0k3 = *(const half8*)(p_ + 192); \
    S##1k0 = *(const half8*)(p_ + 256);  S##1k1 = *(const half8*)(p_ + 320); \
    S##1k2 = *(const half8*)(p_ + 384);  S##1k3 = *(const half8*)(p_ + 448); }

#define LOADW(tt) { const float* p_ = bP + ((tt) << 6); \
    W0 = *(const float4*)p_;       W1 = *(const float4*)(p_ + 4); \
    W2 = *(const float4*)(p_ + 8); W3 = *(const float4*)(p_ + 12); }

#define STOREB(buf) { uint4 u0, u1; \
    u0.x = pk2h(W0.x, W0.y); u0.y = pk2h(W0.z, W0.w); \
    u0.z = pk2h(W1.x, W1.y); u0.w = pk2h(W1.z, W1.w); \
    u1.x = pk2h(W2.x, W2.y); u1.y = pk2h(W2.z, W2.w); \
    u1.z = pk2h(W3.x, W3.y); u1.w = pk2h(W3.z, W3.w); \
    Bs[buf][wi0] = u0; Bs[buf][wi1] = u1; \
    nyacc = fmaf(W0.x, W0.x, nyacc); nyacc = fmaf(W0.y, W0.y, nyacc); \
    nyacc = fmaf(W0.z, W0.z, nyacc); nyacc = fmaf(W0.w, W0.w, nyacc); \
    nyacc = fmaf(W1.x, W1.x, nyacc); nyacc = fmaf(W1.y, W1.y, nyacc); \
    nyacc = fmaf(W1.z, W1.z, nyacc); nyacc = fmaf(W1.w, W1.w, nyacc); \
    nyacc = fmaf(W2.x, W2.x, nyacc); nyacc = fmaf(W2.y, W2.y, nyacc); \
    nyacc = fmaf(W2.z, W2.z, nyacc); nyacc = fmaf(W2.w, W2.w, nyacc); \
    nyacc = fmaf(W3.x, W3.x, nyacc); nyacc = fmaf(W3.y, W3.y, nyacc); \
    nyacc = fmaf(W3.z, W3.z, nyacc); nyacc = fmaf(W3.w, W3.w, nyacc); }

#define LDB01(buf) { b00 = *(const half8*)&Bs[buf][i00]; b01 = *(const half8*)&Bs[buf][i01]; \
                     b10 = *(const half8*)&Bs[buf][i10]; b11 = *(const half8*)&Bs[buf][i11]; }
#define LDB23(buf) { b02 = *(const half8*)&Bs[buf][i02]; b03 = *(const half8*)&Bs[buf][i03]; \
                     b12 = *(const half8*)&Bs[buf][i12]; b13 = *(const half8*)&Bs[buf][i13]; }

#define MFMA8_01(Ax) { __builtin_amdgcn_s_setprio(1); \
    acc00 = MF(Ax##0k0, b00, acc00); acc01 = MF(Ax##0k0, b10, acc01); \
    acc10 = MF(Ax##1k0, b00, acc10); acc11 = MF(Ax##1k0, b10, acc11); \
    acc00 = MF(Ax##0k1, b01, acc00); acc01 = MF(Ax##0k1, b11, acc01); \
    acc10 = MF(Ax##1k1, b01, acc10); acc11 = MF(Ax##1k1, b11, acc11); \
    __builtin_amdgcn_s_setprio(0); }
#define MFMA8_23(Ax) { __builtin_amdgcn_s_setprio(1); \
    acc00 = MF(Ax##0k2, b02, acc00); acc01 = MF(Ax##0k2, b12, acc01); \
    acc10 = MF(Ax##1k2, b02, acc10); acc11 = MF(Ax##1k2, b12, acc11); \
    acc00 = MF(Ax##0k3, b03, acc00); acc01 = MF(Ax##0k3, b13, acc01); \
    acc10 = MF(Ax##1k3, b03, acc10); acc11 = MF(Ax##1k3, b13, acc11); \
    __builtin_amdgcn_s_setprio(0); }

#define SBR __builtin_amdgcn_sched_barrier(0)
#define LG0 asm volatile("s_waitcnt lgkmcnt(0)" ::: "memory")

#define TILE(cur, tt, AC, AN, GA, GW) do { \
    LDB01(cur); \
    if (GA) LOADA(AN, (tt) + 1); \
    SBR; __builtin_amdgcn_s_barrier(); LG0; SBR; \
    MFMA8_01(AC); \
    SBR; __builtin_amdgcn_s_barrier(); \
    LDB23(cur); \
    if (GA) STOREB((cur) ^ 1); \
    if (GW) LOADW((tt) + 2); \
    SBR; __builtin_amdgcn_s_barrier(); LG0; SBR; \
    MFMA8_23(AC); \
    SBR; __builtin_amdgcn_s_barrier(); \
} while (0)

    // ---- prologue ----
    LOADW(0);
    LOADA(C, 0);
    STOREB(0);     // waits W(0) via compiler vmcnt
    LOADW(1);
    SBR; LG0; SBR;
    __builtin_amdgcn_s_barrier();

    for (int t = 0; t < 62; t += 2) {
        TILE(0, t,     C, N, 1, 1);
        TILE(1, t + 1, N, C, 1, 1);
    }
    TILE(0, 62, C, N, 1, 0);
    TILE(1, 63, N, C, 0, 0);

    // ---- fused ||w_y|| ----
    float s = nyacc;
    s += __shfl_xor(s, 1);
    s += __shfl_xor(s, 2);
    if (q == 0) ny_inv[rB] = 1.0f / fmaxf(sqrtf(s), 1e-12f);
    if (tid == 0) lcnt = 0u;
    __syncthreads();

    // ---- epilogue: gated scores, block-row max, candidate append ----
    // acc{mi}{ni}[v] = S[wm*64 + mi*32 + (v&3)+8*(v>>2)+4*kh][wn*64 + ni*32 + (lane&31)]
    const int yloc0 = (wn << 6) + (lane & 31);
    const int yloc1 = yloc0 + 32;
    const float scl0 = ny_inv[yloc0], scl1 = ny_inv[yloc1];
    const int act0 = (age[y0 + yloc0] >= 1), act1 = (age[y0 + yloc1] >= 1);
    const int rbase = (wm << 6) + (kh << 2);

#define ROWMAX_MI(ACC0, ACC1, mibase) \
    _Pragma("unroll") for (int v = 0; v < 16; ++v) { \
        float bv = fmaxf(act0 ? ACC0[v] * scl0 : 0.0f, act1 ? ACC1[v] * scl1 : 0.0f); \
        _Pragma("unroll") for (int off = 1; off < 32; off <<= 1) \
            bv = fmaxf(bv, __shfl_xor(bv, off)); \
        if ((lane & 31) == 0) comb[rbase + (mibase) + (v & 3) + ((v >> 2) << 3)][wn] = bv; \
    }
    ROWMAX_MI(acc00, acc01, 0)
    ROWMAX_MI(acc10, acc11, 32)
    __syncthreads();
    if (tid < 256) {
        const float rm = fmaxf(comb[tid][0], comb[tid][1]);
        cand[(size_t)(b0 + tid) * 256 + blockIdx.y] = rm;
        rowmaxs[tid] = rm;
    }
    __syncthreads();

    // LDS-buffered append: per-lane LDS atomic, ONE global atomic per block.
#define APPEND_MI(ACC0, ACC1, mibase) \
    _Pragma("unroll") for (int v = 0; v < 16; ++v) { \
        const int r = rbase + (mibase) + (v & 3) + ((v >> 2) << 3); \
        const float thr = rowmaxs[r] - TAU; \
        if (act0) { const float sc = ACC0[v] * scl0; \
            if (sc >= thr) { const unsigned ix = atomicAdd(&lcnt, 1u); \
                if (ix < LCAP) lent[ix] = make_float2(sc, \
                    __uint_as_float(((unsigned)(b0 + r) << 16) | (unsigned)(y0 + yloc0))); } } \
        if (act1) { const float sc = ACC1[v] * scl1; \
            if (sc >= thr) { const unsigned ix = atomicAdd(&lcnt, 1u); \
                if (ix < LCAP) lent[ix] = make_float2(sc, \
                    __uint_as_float(((unsigned)(b0 + r) << 16) | (unsigned)(y0 + yloc1))); } } \
    }
    APPEND_MI(acc00, acc01, 0)
    APPEND_MI(acc10, acc11, 32)
    __syncthreads();
    if (tid == 0) gbase = atomicAdd(cnt, min(lcnt, LCAP));
    __syncthreads();
    const unsigned nLoc = min(lcnt, LCAP);
    for (unsigned i = tid; i < nLoc; i += 512) {
        const unsigned gi = gbase + i;
        if (gi < CAP) ent[gi] = lent[i];
    }
#undef MF
#undef LOADA
#undef LOADW
#undef STOREB
#undef LDB01
#undef LDB23
#undef MFMA8_01
#undef MFMA8_23
#undef SBR
#undef LG0
#undef TILE
#undef BIDX
#undef ROWMAX_MI
#undef APPEND_MI
}

__global__ __launch_bounds__(256) void reduce_gmax(const float* __restrict__ cand,
                                                   float* __restrict__ gmax) {
    const int b = blockIdx.x, t = threadIdx.x;
    float m = cand[(size_t)b * 256 + t];
    #pragma unroll
    for (int off = 32; off; off >>= 1) m = fmaxf(m, __shfl_xor(m, off));
    __shared__ float sm[4];
    if ((t & 63) == 0) sm[t >> 6] = m;
    __syncthreads();
    if (t == 0) gmax[b] = fmaxf(fmaxf(sm[0], sm[1]), fmaxf(sm[2], sm[3]));
}

// exact f32 rescore of survivors; one wave per entry
__global__ __launch_bounds__(256) void rescore(
    const float* __restrict__ x, const float* __restrict__ w,
    const float* __restrict__ gmax, const float2* __restrict__ ent,
    const unsigned* __restrict__ cnt, ull* __restrict__ win)
{
    const unsigned n = min(*cnt, CAP);
    const int lane = threadIdx.x & 63;
    const unsigned wid = (blockIdx.x * 256 + threadIdx.x) >> 6;
    const unsigned nwv = (gridDim.x * 256) >> 6;
    for (unsigned e = wid; e < n; e += nwv) {
        const float2 en = ent[e];
        const unsigned by = __float_as_uint(en.y);
        const unsigned b = by >> 16, y = by & 0xffffu;
        if (en.x < gmax[b] - TAU) continue;
        const float4* xr = (const float4*)(x + (size_t)b * 4096);
        const float4* wr = (const float4*)(w + (size_t)y * 4096);
        float s = 0.f, nn = 0.f;
        #pragma unroll
        for (int k = 0; k < 16; ++k) {
            const float4 xv = xr[(k << 6) + lane];
            const float4 wv = wr[(k << 6) + lane];
            s = fmaf(xv.x, wv.x, s); s = fmaf(xv.y, wv.y, s);
            s = fmaf(xv.z, wv.z, s); s = fmaf(xv.w, wv.w, s);
            nn = fmaf(wv.x, wv.x, nn); nn = fmaf(wv.y, wv.y, nn);
            nn = fmaf(wv.z, wv.z, nn); nn = fmaf(wv.w, wv.w, nn);
        }
        #pragma unroll
        for (int off = 32; off; off >>= 1) {
            s += __shfl_xor(s, off);
            nn += __shfl_xor(nn, off);
        }
        if (lane == 0) {
            const float sc = s / fmaxf(sqrtf(nn), 1e-12f);
            atomicMax(win + b, packkey(sc, y));
        }
    }
}

__global__ __launch_bounds__(256) void gather_out(const float* __restrict__ y2z,
                                                  const float* __restrict__ nz,
                                                  const ull* __restrict__ win,
                                                  float* __restrict__ out) {
    const int g = blockIdx.x * 256 + threadIdx.x;
    if (g >= 512 * 1000) return;
    const int b = g / 1000, z = g - b * 1000;
    const unsigned lo = (unsigned)(win[b] & 0xffffffffull);
    const int yw = (int)(0x7FFFFFFFu - lo);
    out[g] = y2z[(size_t)z * 32768 + yw] / fmaxf(nz[z], 1e-12f);
}

extern "C" void kernel_launch(void* const* d_in, const int* in_sizes, int n_in,
                              void* d_out, int out_size, void* d_ws, size_t ws_size,
                              hipStream_t stream) {
    const float* x     = (const float*)d_in[0];
    const float* x2y_w = (const float*)d_in[2];
    const float* y2z_w = (const float*)d_in[3];
    const int*   y_age = (const int*)d_in[4];
    float* out = (float*)d_out;

    // ws layout (bytes)
    char* p = (char*)d_ws;
    float*    cand = (float*)p;                       // 512*256*4  = 524288
    float*    nz   = (float*)(p + 524288);            // 4096
    float*    gmax = (float*)(p + 528384);            // 2048
    ull*      win  = (ull*)(p + 530432);              // 4096
    unsigned* cnt  = (unsigned*)(p + 534528);         // 64
    uint4*    xf16 = (uint4*)(p + 534592);            // 4194304
    float2*   ent  = (float2*)(p + 4728896);          // CAP*8 = 12582912

    init_ctrl<<<1, 512, 0, stream>>>(y_age, win, cnt);
    convert_x<<<512, 512, 0, stream>>>(x, xf16);
    row_norms<<<1000, 256, 0, stream>>>(y2z_w, nz, 32768);

    gemm_f16<<<dim3(2, 256), 512, 0, stream>>>(x2y_w, xf16, y_age, cand, ent, cnt);
    reduce_gmax<<<512, 256, 0, stream>>>(cand, gmax);
    rescore<<<256, 256, 0, stream>>>(x, x2y_w, gmax, ent, cnt, win);
    gather_out<<<(512 * 1000 + 255) / 256, 256, 0, stream>>>(y2z_w, nz, win, out);
}

// Round 9
// 372.103 us; speedup vs baseline: 4.1943x; 1.0226x over previous
//
#include <hip/hip_runtime.h>
#include <math.h>

// DN test-mode forward, filter+rescore:
//  1) convert x -> f16 fragment-linear tiles (A staged via global_load_lds)
//  2) f16 single-pairing MFMA GEMM, 256x256 tile, 1 block/CU, A+B in dbuf LDS,
//     4 phases/K-tile; fused ||w_y|| + per-row max + LDS-buffered candidate append
//  3) global approx max per batch (gmax)
//  4) exact f32 rescore of survivors (ballot-compacted scan), packed atomicMax
//     winner (seeded with (0.0, firstInactive) covering gated-zero candidates)
//  5) gather out[b,z] = y2z[z,winner]/||y2z[z,:]||

typedef _Float16 half8 __attribute__((ext_vector_type(8)));
typedef __attribute__((ext_vector_type(16))) float f32x16;
typedef unsigned long long ull;

#define TAU 0.006f
#define CAP 1572864u
#define LCAP 1024u

__device__ __forceinline__ unsigned pk2h(float a, float b) {
    union { _Float16 h; unsigned short u; } ca, cb;
    ca.h = (_Float16)a; cb.h = (_Float16)b;   // RNE
    return (unsigned)ca.u | ((unsigned)cb.u << 16);
}

// monotone-float key, smaller y wins ties
__device__ __forceinline__ ull packkey(float v, unsigned y) {
    unsigned m = __float_as_uint(v);
    m = (v >= 0.f) ? (m | 0x80000000u) : ~m;
    return ((ull)m << 32) | (ull)(0x7FFFFFFFu - y);
}

#define GLDS(gp, lp) __builtin_amdgcn_global_load_lds( \
    (const __attribute__((address_space(1))) void*)(gp), \
    (__attribute__((address_space(3))) void*)(lp), 16, 0, 0)

__global__ __launch_bounds__(512) void init_ctrl(const int* __restrict__ age,
                                                 ull* __restrict__ win,
                                                 unsigned* __restrict__ cnt) {
    const int t = threadIdx.x;
    int fi = 0x7fffffff;
    for (int y = t; y < 32768; y += 512)
        if (age[y] < 1) fi = min(fi, y);
    __shared__ int red[512];
    red[t] = fi;
    __syncthreads();
    for (int s = 256; s; s >>= 1) {
        if (t < s) red[t] = min(red[t], red[t + s]);
        __syncthreads();
    }
    const int f = red[0];
    const ull seed = (f < 32768) ? packkey(0.0f, (unsigned)f) : packkey(-1e30f, 0u);
    win[t] = seed;                      // t < 512 = B
    if (t == 0) *cnt = 0u;
}

// x -> f16, fragment-linear per (t, bx): o = (((t*2+bx)*8 + rg)*4 + ks)*64 + lane
__global__ __launch_bounds__(512) void convert_x(const float* __restrict__ x,
                                                 uint4* __restrict__ xf16) {
    const int o = blockIdx.x * 512 + threadIdx.x;   // 262144
    const int lane = o & 63;
    const int ks = (o >> 6) & 3;
    const int rg = (o >> 8) & 7;
    const int bx = (o >> 11) & 1;
    const int t  = o >> 12;
    const int row = (bx << 8) + (rg << 5) + (lane & 31);
    const int col = (t << 6) + (ks << 4) + ((lane >> 5) << 3);
    const float* src = x + (size_t)row * 4096 + col;
    const float4 a = *(const float4*)src;
    const float4 b = *(const float4*)(src + 4);
    uint4 u;
    u.x = pk2h(a.x, a.y); u.y = pk2h(a.z, a.w);
    u.z = pk2h(b.x, b.y); u.w = pk2h(b.z, b.w);
    xf16[o] = u;
}

__global__ __launch_bounds__(256) void row_norms(const float* __restrict__ src,
                                                 float* __restrict__ dst, int cols) {
    const int r = blockIdx.x;
    const float* row = src + (size_t)r * cols;
    const int t = threadIdx.x;
    float s = 0.f;
    const int nIter = cols >> 10;
    for (int i = 0; i < nIter; ++i) {
        const float4 v = *reinterpret_cast<const float4*>(row + (((i << 8) + t) << 2));
        s = fmaf(v.x, v.x, s); s = fmaf(v.y, v.y, s);
        s = fmaf(v.z, v.z, s); s = fmaf(v.w, v.w, s);
    }
    #pragma unroll
    for (int off = 32; off; off >>= 1) s += __shfl_down(s, off);
    __shared__ float red[4];
    if ((t & 63) == 0) red[t >> 6] = s;
    __syncthreads();
    if (t == 0) dst[r] = sqrtf(red[0] + red[1] + red[2] + red[3]);
}

__global__ __launch_bounds__(512, 2) void gemm_f16(
    const float* __restrict__ w,      // [32768][4096]
    const uint4* __restrict__ xf16,   // pre-converted x, fragment-linear
    const int*  __restrict__ age,
    float* __restrict__ cand,         // [512][128] block-row approx max
    float2* __restrict__ ent,         // candidate list
    unsigned* __restrict__ cnt)
{
    __shared__ uint4 Al[2][2048];     // A tile 256x64 f16, fragment-linear
    __shared__ uint4 Bl[2][2048];     // B tile 256x64 f16, swizzled 16B slots
    __shared__ float ny_inv[256];
    __shared__ float comb[256][2];
    __shared__ float rowmaxs[256];
    __shared__ float2 lent[LCAP];
    __shared__ unsigned lcnt, gbase;

    const int tid = threadIdx.x;
    const int bx = blockIdx.x;        // BM half: 0,1
    const int b0 = bx << 8;
    const int y0 = blockIdx.y << 8;   // BN = 256

    // W staging: thread covers rows rB, rB+128; cols q*16..q*16+15 per tile
    const int rB = tid >> 2, q = tid & 3;
    const int rB2 = rB + 128;
    const int wi00 = (rB  << 3) + (((q << 1)    ) ^ (rB  & 7));
    const int wi01 = (rB  << 3) + (((q << 1) | 1) ^ (rB  & 7));
    const int wi10 = (rB2 << 3) + (((q << 1)    ) ^ (rB2 & 7));
    const int wi11 = (rB2 << 3) + (((q << 1) | 1) ^ (rB2 & 7));
    const float* bP0 = w + (size_t)(y0 + rB ) * 4096 + (q << 4);
    const float* bP1 = w + (size_t)(y0 + rB2) * 4096 + (q << 4);

    // MFMA decomposition: 8 waves = 4 wm x 2 wn, wave tile 64 rows x 128 cols
    const int lane = tid & 63, wave = tid >> 6;
    const int wm = wave >> 1, wn = wave & 1;
    const int kh = lane >> 5;
    const int iA0 = (wm << 9) + lane;   // rg = wm*2+mi; idx = rg*256 + ks*64 + lane
    const int iA1 = iA0 + 256;

    const int r0 = (wn << 7) + (lane & 31);
    const int r1 = r0 + 32, r2 = r0 + 64, r3 = r0 + 96;
    const int rb0 = r0 << 3, rb1 = r1 << 3, rb2 = r2 << 3, rb3 = r3 << 3;
    const int c0 = r0 & 7, c1 = r1 & 7, c2 = r2 & 7, c3 = r3 & 7;

    f32x16 am0n0 = (f32x16)0.f, am0n1 = (f32x16)0.f, am0n2 = (f32x16)0.f, am0n3 = (f32x16)0.f;
    f32x16 am1n0 = (f32x16)0.f, am1n1 = (f32x16)0.f, am1n2 = (f32x16)0.f, am1n3 = (f32x16)0.f;

    half8 a0, a1, fb0, fb1, fb2, fb3;
    float4 W0, W1, W2, W3, W4, W5, W6, W7;
    float ny0 = 0.f, ny1 = 0.f;

#define MF(a, b, c) __builtin_amdgcn_mfma_f32_32x32x16_f16(a, b, c, 0, 0, 0)
#define SBR __builtin_amdgcn_sched_barrier(0)
#define LG0 asm volatile("s_waitcnt lgkmcnt(0)" ::: "memory")

#define STAGEA(buf, tt) { \
    const uint4* g_ = xf16 + ((size_t)((((tt) << 1) | bx)) << 11); \
    GLDS(g_ + tid,        &Al[buf][tid]); \
    GLDS(g_ + 512 + tid,  &Al[buf][512 + tid]); \
    GLDS(g_ + 1024 + tid, &Al[buf][1024 + tid]); \
    GLDS(g_ + 1536 + tid, &Al[buf][1536 + tid]); }

#define LOADW(tt) { \
    const float* p_ = bP0 + ((tt) << 6); \
    W0 = *(const float4*)p_;        W1 = *(const float4*)(p_ + 4); \
    W2 = *(const float4*)(p_ + 8);  W3 = *(const float4*)(p_ + 12); \
    const float* p2_ = bP1 + ((tt) << 6); \
    W4 = *(const float4*)p2_;       W5 = *(const float4*)(p2_ + 4); \
    W6 = *(const float4*)(p2_ + 8); W7 = *(const float4*)(p2_ + 12); }

#define STOREB(buf) { uint4 u_; \
    u_.x = pk2h(W0.x, W0.y); u_.y = pk2h(W0.z, W0.w); \
    u_.z = pk2h(W1.x, W1.y); u_.w = pk2h(W1.z, W1.w); \
    Bl[buf][wi00] = u_; \
    u_.x = pk2h(W2.x, W2.y); u_.y = pk2h(W2.z, W2.w); \
    u_.z = pk2h(W3.x, W3.y); u_.w = pk2h(W3.z, W3.w); \
    Bl[buf][wi01] = u_; \
    u_.x = pk2h(W4.x, W4.y); u_.y = pk2h(W4.z, W4.w); \
    u_.z = pk2h(W5.x, W5.y); u_.w = pk2h(W5.z, W5.w); \
    Bl[buf][wi10] = u_; \
    u_.x = pk2h(W6.x, W6.y); u_.y = pk2h(W6.z, W6.w); \
    u_.z = pk2h(W7.x, W7.y); u_.w = pk2h(W7.z, W7.w); \
    Bl[buf][wi11] = u_; \
    ny0 = fmaf(W0.x, W0.x, ny0); ny0 = fmaf(W0.y, W0.y, ny0); \
    ny0 = fmaf(W0.z, W0.z, ny0); ny0 = fmaf(W0.w, W0.w, ny0); \
    ny0 = fmaf(W1.x, W1.x, ny0); ny0 = fmaf(W1.y, W1.y, ny0); \
    ny0 = fmaf(W1.z, W1.z, ny0); ny0 = fmaf(W1.w, W1.w, ny0); \
    ny0 = fmaf(W2.x, W2.x, ny0); ny0 = fmaf(W2.y, W2.y, ny0); \
    ny0 = fmaf(W2.z, W2.z, ny0); ny0 = fmaf(W2.w, W2.w, ny0); \
    ny0 = fmaf(W3.x, W3.x, ny0); ny0 = fmaf(W3.y, W3.y, ny0); \
    ny0 = fmaf(W3.z, W3.z, ny0); ny0 = fmaf(W3.w, W3.w, ny0); \
    ny1 = fmaf(W4.x, W4.x, ny1); ny1 = fmaf(W4.y, W4.y, ny1); \
    ny1 = fmaf(W4.z, W4.z, ny1); ny1 = fmaf(W4.w, W4.w, ny1); \
    ny1 = fmaf(W5.x, W5.x, ny1); ny1 = fmaf(W5.y, W5.y, ny1); \
    ny1 = fmaf(W5.z, W5.z, ny1); ny1 = fmaf(W5.w, W5.w, ny1); \
    ny1 = fmaf(W6.x, W6.x, ny1); ny1 = fmaf(W6.y, W6.y, ny1); \
    ny1 = fmaf(W6.z, W6.z, ny1); ny1 = fmaf(W6.w, W6.w, ny1); \
    ny1 = fmaf(W7.x, W7.x, ny1); ny1 = fmaf(W7.y, W7.y, ny1); \
    ny1 = fmaf(W7.z, W7.z, ny1); ny1 = fmaf(W7.w, W7.w, ny1); }

#define MFMA8 { __builtin_amdgcn_s_setprio(1); \
    am0n0 = MF(a0, fb0, am0n0); am0n1 = MF(a0, fb1, am0n1); \
    am1n0 = MF(a1, fb0, am1n0); am1n1 = MF(a1, fb1, am1n1); \
    am0n2 = MF(a0, fb2, am0n2); am0n3 = MF(a0, fb3, am0n3); \
    am1n2 = MF(a1, fb2, am1n2); am1n3 = MF(a1, fb3, am1n3); \
    __builtin_amdgcn_s_setprio(0); }

#define PHASE(cur, ks, EXTRA) { \
    a0  = *(const half8*)&Al[cur][iA0 + ((ks) << 6)]; \
    a1  = *(const half8*)&Al[cur][iA1 + ((ks) << 6)]; \
    fb0 = *(const half8*)&Bl[cur][rb0 + ((((ks) << 1) | kh) ^ c0)]; \
    fb1 = *(const half8*)&Bl[cur][rb1 + ((((ks) << 1) | kh) ^ c1)]; \
    fb2 = *(const half8*)&Bl[cur][rb2 + ((((ks) << 1) | kh) ^ c2)]; \
    fb3 = *(const half8*)&Bl[cur][rb3 + ((((ks) << 1) | kh) ^ c3)]; \
    EXTRA \
    SBR; __builtin_amdgcn_s_barrier(); LG0; SBR; \
    MFMA8; \
    SBR; __builtin_amdgcn_s_barrier(); }

// One BK=64 tile = 4 phases. GLDS (oldest vmem) auto-drained by the compiler's
// wait for the newer W-load regs at STOREB (FIFO retire) -> no manual vmcnt.
#define TILE(cur, tt, GA) { \
    PHASE(cur, 0, if (GA) { STAGEA((cur) ^ 1, (tt) + 1); LOADW((tt) + 1); }) \
    PHASE(cur, 1, ) \
    PHASE(cur, 2, ) \
    PHASE(cur, 3, if (GA) { STOREB((cur) ^ 1); }) }

    // ---- prologue: tile 0 into buf0 ----
    STAGEA(0, 0);
    LOADW(0);
    STOREB(0);     // waits W(0) loads (drains GLDS(0) too, FIFO)
    SBR; LG0; SBR;
    __builtin_amdgcn_s_barrier();

    for (int t = 0; t < 62; t += 2) {
        TILE(0, t, 1)
        TILE(1, t + 1, 1)
    }
    TILE(0, 62, 1)
    TILE(1, 63, 0)

    // ---- fused ||w_y|| ----
    float s_ = ny0;
    s_ += __shfl_xor(s_, 1); s_ += __shfl_xor(s_, 2);
    float s2_ = ny1;
    s2_ += __shfl_xor(s2_, 1); s2_ += __shfl_xor(s2_, 2);
    if (q == 0) {
        ny_inv[rB]  = 1.0f / fmaxf(sqrtf(s_),  1e-12f);
        ny_inv[rB2] = 1.0f / fmaxf(sqrtf(s2_), 1e-12f);
    }
    if (tid == 0) lcnt = 0u;
    __syncthreads();

    // ---- epilogue: gated scores, per-row max, candidate append ----
    // am{mi}n{ni}[v] = S[wm*64+mi*32+(v&3)+8*(v>>2)+4*kh][wn*128+ni*32+(lane&31)]
    const float scl0 = ny_inv[r0], scl1 = ny_inv[r1], scl2 = ny_inv[r2], scl3 = ny_inv[r3];
    const int act0 = age[y0 + r0] >= 1, act1 = age[y0 + r1] >= 1;
    const int act2 = age[y0 + r2] >= 1, act3 = age[y0 + r3] >= 1;
    const int yb0 = y0 + r0, yb1 = y0 + r1, yb2 = y0 + r2, yb3 = y0 + r3;
    const int rbase = (wm << 6) + (kh << 2);

#define ROWMAX(A0, A1, A2, A3, mibase) \
    _Pragma("unroll") for (int v = 0; v < 16; ++v) { \
        float bv = fmaxf( \
            fmaxf(act0 ? A0[v] * scl0 : 0.f, act1 ? A1[v] * scl1 : 0.f), \
            fmaxf(act2 ? A2[v] * scl2 : 0.f, act3 ? A3[v] * scl3 : 0.f)); \
        _Pragma("unroll") for (int off = 1; off < 32; off <<= 1) \
            bv = fmaxf(bv, __shfl_xor(bv, off)); \
        if ((lane & 31) == 0) comb[rbase + (mibase) + (v & 3) + ((v >> 2) << 3)][wn] = bv; \
    }
    ROWMAX(am0n0, am0n1, am0n2, am0n3, 0)
    ROWMAX(am1n0, am1n1, am1n2, am1n3, 32)
    __syncthreads();
    if (tid < 256) {
        const float rm = fmaxf(comb[tid][0], comb[tid][1]);
        cand[(size_t)(b0 + tid) * 128 + blockIdx.y] = rm;
        rowmaxs[tid] = rm;
    }
    __syncthreads();

#define APP1(ACv, actk, sclk, ybk, r_) { \
    if (actk) { const float sc_ = (ACv) * sclk; \
        if (sc_ >= rowmaxs[r_] - TAU) { \
            const unsigned ix_ = atomicAdd(&lcnt, 1u); \
            if (ix_ < LCAP) lent[ix_] = make_float2(sc_, \
                __uint_as_float(((unsigned)(b0 + r_) << 16) | (unsigned)(ybk))); } } }

#define APPEND(A0, A1, A2, A3, mibase) \
    _Pragma("unroll") for (int v = 0; v < 16; ++v) { \
        const int r_ = rbase + (mibase) + (v & 3) + ((v >> 2) << 3); \
        APP1(A0[v], act0, scl0, yb0, r_) \
        APP1(A1[v], act1, scl1, yb1, r_) \
        APP1(A2[v], act2, scl2, yb2, r_) \
        APP1(A3[v], act3, scl3, yb3, r_) }
    APPEND(am0n0, am0n1, am0n2, am0n3, 0)
    APPEND(am1n0, am1n1, am1n2, am1n3, 32)
    __syncthreads();
    if (tid == 0) gbase = atomicAdd(cnt, min(lcnt, LCAP));
    __syncthreads();
    const unsigned nL = min(lcnt, LCAP);
    for (unsigned i = tid; i < nL; i += 512) {
        const unsigned gi = gbase + i;
        if (gi < CAP) ent[gi] = lent[i];
    }
#undef MF
#undef SBR
#undef LG0
#undef STAGEA
#undef LOADW
#undef STOREB
#undef MFMA8
#undef PHASE
#undef TILE
#undef ROWMAX
#undef APP1
#undef APPEND
}

__global__ __launch_bounds__(128) void reduce_gmax(const float* __restrict__ cand,
                                                   float* __restrict__ gmax) {
    const int b = blockIdx.x, t = threadIdx.x;
    float m = cand[(size_t)b * 128 + t];
    #pragma unroll
    for (int off = 32; off; off >>= 1) m = fmaxf(m, __shfl_xor(m, off));
    __shared__ float sm[2];
    if ((t & 63) == 0) sm[t >> 6] = m;
    __syncthreads();
    if (t == 0) gmax[b] = fmaxf(sm[0], sm[1]);
}

// exact f32 rescore; ballot-compacted scan, wave-per-survivor dot product
__global__ __launch_bounds__(256) void rescore(
    const float* __restrict__ x, const float* __restrict__ w,
    const float* __restrict__ gmax, const float2* __restrict__ ent,
    const unsigned* __restrict__ cnt, ull* __restrict__ win)
{
    const unsigned n = min(*cnt, CAP);
    const int lane = threadIdx.x & 63;
    const unsigned wid = (blockIdx.x * 256 + threadIdx.x) >> 6;
    const unsigned nwv = (gridDim.x * 256) >> 6;
    for (unsigned base = wid << 6; base < n; base += (nwv << 6)) {
        const unsigned e = base + (unsigned)lane;
        unsigned by = 0u;
        bool ok = false;
        if (e < n) {
            const float2 en = ent[e];
            by = __float_as_uint(en.y);
            ok = en.x >= gmax[by >> 16] - TAU;
        }
        ull m = __ballot(ok);
        while (m) {
            const int s = __ffsll((ull)m) - 1;
            m &= m - 1;
            const unsigned bys = __shfl(by, s);
            const unsigned b = bys >> 16, y = bys & 0xffffu;
            const float4* xr = (const float4*)(x + (size_t)b * 4096);
            const float4* wr = (const float4*)(w + (size_t)y * 4096);
            float sdot = 0.f, nn = 0.f;
            #pragma unroll
            for (int k = 0; k < 16; ++k) {
                const float4 xv = xr[(k << 6) + lane];
                const float4 wv = wr[(k << 6) + lane];
                sdot = fmaf(xv.x, wv.x, sdot); sdot = fmaf(xv.y, wv.y, sdot);
                sdot = fmaf(xv.z, wv.z, sdot); sdot = fmaf(xv.w, wv.w, sdot);
                nn = fmaf(wv.x, wv.x, nn); nn = fmaf(wv.y, wv.y, nn);
                nn = fmaf(wv.z, wv.z, nn); nn = fmaf(wv.w, wv.w, nn);
            }
            #pragma unroll
            for (int off = 32; off; off >>= 1) {
                sdot += __shfl_xor(sdot, off);
                nn   += __shfl_xor(nn, off);
            }
            if (lane == 0) {
                const float sc = sdot / fmaxf(sqrtf(nn), 1e-12f);
                atomicMax(win + b, packkey(sc, y));
            }
        }
    }
}

__global__ __launch_bounds__(256) void gather_out(const float* __restrict__ y2z,
                                                  const float* __restrict__ nz,
                                                  const ull* __restrict__ win,
                                                  float* __restrict__ out) {
    const int g = blockIdx.x * 256 + threadIdx.x;
    if (g >= 512 * 1000) return;
    const int b = g / 1000, z = g - b * 1000;
    const unsigned lo = (unsigned)(win[b] & 0xffffffffull);
    const int yw = (int)(0x7FFFFFFFu - lo);
    out[g] = y2z[(size_t)z * 32768 + yw] / fmaxf(nz[z], 1e-12f);
}

extern "C" void kernel_launch(void* const* d_in, const int* in_sizes, int n_in,
                              void* d_out, int out_size, void* d_ws, size_t ws_size,
                              hipStream_t stream) {
    const float* x     = (const float*)d_in[0];
    const float* x2y_w = (const float*)d_in[2];
    const float* y2z_w = (const float*)d_in[3];
    const int*   y_age = (const int*)d_in[4];
    float* out = (float*)d_out;

    // ws layout (bytes)
    char* p = (char*)d_ws;
    float*    cand = (float*)p;                       // 512*128*4 = 262144
    float*    nz   = (float*)(p + 262144);            // 4096
    float*    gmax = (float*)(p + 266240);            // 2048
    ull*      win  = (ull*)(p + 268288);              // 4096
    unsigned* cnt  = (unsigned*)(p + 272384);         // 64
    uint4*    xf16 = (uint4*)(p + 272448);            // 4 MB
    float2*   ent  = (float2*)(p + 4466752);          // CAP*8

    init_ctrl<<<1, 512, 0, stream>>>(y_age, win, cnt);
    convert_x<<<512, 512, 0, stream>>>(x, xf16);
    row_norms<<<1000, 256, 0, stream>>>(y2z_w, nz, 32768);

    gemm_f16<<<dim3(2, 128), 512, 0, stream>>>(x2y_w, xf16, y_age, cand, ent, cnt);
    reduce_gmax<<<512, 128, 0, stream>>>(cand, gmax);
    rescore<<<256, 256, 0, stream>>>(x, x2y_w, gmax, ent, cnt, win);
    gather_out<<<(512 * 1000 + 255) / 256, 256, 0, stream>>>(y2z_w, nz, win, out);
}